// Round 13
// baseline (452.543 us; speedup 1.0000x reference)
//
#include <hip/hip_runtime.h>
#include <math.h>

#define HDIM 768
#define BDIM 256
#define INDIM 64
#define NLAYERS 4
#define PDIM 8
#define KSPLIT 16     // trop k-split: 16 slots x 48k
#define KLEN 48
#define CHK 16
#define TR 128
#define TC 64
#define NBLKP 256     // physical blocks: 1/CU guaranteed resident (LDS 48KB, VGPR<=256)
#define NTHR 512      // 2 logical 256-thr sub-blocks per block
#define WSZ ((size_t)HDIM * HDIM)
#define NBH ((size_t)BDIM * HDIM)

typedef short bf16x8 __attribute__((ext_vector_type(8)));
typedef float f32x4 __attribute__((ext_vector_type(4)));

__device__ __forceinline__ float sigmoidf_(float x) { return 1.f / (1.f + expf(-x)); }
__device__ __forceinline__ float geluf_(float x) { return 0.5f * x * (1.f + erff(x * 0.70710678118654752f)); }
__device__ __forceinline__ unsigned short f2bf(float f) {
    unsigned int u = __float_as_uint(f);
    u += 0x7FFFu + ((u >> 16) & 1u);          // RNE
    return (unsigned short)(u >> 16);
}
__device__ __forceinline__ void gload_lds16(const float* g, float* l) {
    __builtin_amdgcn_global_load_lds((const __attribute__((address_space(1))) void*)g,
                                     (__attribute__((address_space(3))) void*)l, 16, 0, 0);
}

struct P {
    const float *x, *w_in, *b_in, *ln_g, *ln_b, *trop_w, *trop_b;
    const float *amax, *bmax, *amin, *bmin, *alpha;
    const float *gate_w, *gate_b, *cls_w, *cls_b, *out_g, *out_b, *head_w, *head_b;
    float *out;
    float *h, *hnT, *twT, *p_trop, *p_cls, *p_gate;
    unsigned short *hnB, *wB;
    int *bar;
};

union LdsU {
    struct { float hn[2][CHK][TR]; float wt[2][CHK][TC]; } t[2];   // 49152 B (per-sub trop)
    float tile[64][65];                                            // 16640 B (prep)
    struct { float xs[2][INDIM]; float rbuf[2][16]; } inp;         // LN per-sub
};

// Hand-rolled grid barrier: single-use counter per phase (memset-zeroed on the
// stream before launch).  Device-scope atomics + __threadfence (cross-XCD L2
// wb/inv) per guide G16.  Co-residency is guaranteed by construction (256
// blocks, every CU can host one), so no deadlock is possible.
__device__ __forceinline__ void gbar(int* cnt, int ph) {
    __syncthreads();
    if (threadIdx.x == 0) {
        __threadfence();   // release: drain + L2 writeback (cross-XCD visibility)
        __hip_atomic_fetch_add(&cnt[ph], 1, __ATOMIC_RELAXED, __HIP_MEMORY_SCOPE_AGENT);
        while (__hip_atomic_load(&cnt[ph], __ATOMIC_RELAXED, __HIP_MEMORY_SCOPE_AGENT) < NBLKP)
            __builtin_amdgcn_s_sleep(8);
        __threadfence();   // acquire: invalidate L1/L2 before reading others' data
    }
    __syncthreads();
}

// ---------------------------------------------------------------------------
// ONE persistent kernel, NORMAL launch (cooperative API fails in this env —
// R11/R12 both died at launch).  256 blocks x 512 thr; waves 0-3 / 4-7 form
// two logical 256-thr sub-blocks so the verified R9/R10 phase geometries map
// unchanged.  Phases: prep, input+LN0, 4x(mm[trop fp32 + cg bf16-MFMA] ->
// combine).  8 grid barriers.
// ---------------------------------------------------------------------------
__global__ __launch_bounds__(NTHR, 2) void mega_k(P p)
{
    __shared__ LdsU u;
    const int bx = blockIdx.x;
    const int tid = threadIdx.x;
    const int wave = tid >> 6, lane = tid & 63;
    const int sub = wave >> 2;        // logical sub-block 0/1
    const int wv = wave & 3;          // wave within sub-block
    const int stid = tid & 255;       // tid within sub-block

    // ================= PHASE 0a: weight prep (1728 transpose jobs) ========
    for (int j = bx; j < 1728; j += NBLKP) {
        const int c = tid & 63;
        const int r8 = tid >> 6;      // 0..7
        if (j < 576) {
            // trop_w[l][o][i] -> twT[l][i][o]  (fp32, exact)
            const int l = j / 144, t = j % 144;
            const int a0 = (t / 12) * 64, b0 = (t % 12) * 64;   // a0=o, b0=i
            const float* s = p.trop_w + (size_t)l * WSZ;
            float* d = p.twT + (size_t)l * WSZ;
#pragma unroll
            for (int it = 0; it < 8; ++it) {
                const int r = it * 8 + r8;
                u.tile[r][c] = s[(size_t)(a0 + r) * HDIM + b0 + c];
            }
            __syncthreads();
#pragma unroll
            for (int it = 0; it < 8; ++it) {
                const int r = it * 8 + r8;
                d[(size_t)(b0 + r) * HDIM + a0 + c] = u.tile[c][r];
            }
            __syncthreads();
        } else {
            // cls/gate [k][o] -> wB[zz][o][k] bf16
            const int j2 = j - 576;
            const int zz = j2 / 144, t = j2 % 144;
            const int l = zz >> 1, mat = zz & 1;
            const int a0 = (t / 12) * 64, b0 = (t % 12) * 64;   // a0=o, b0=k
            const float* s = (mat ? p.gate_w : p.cls_w) + (size_t)l * WSZ;
            unsigned short* d = p.wB + (size_t)zz * WSZ;
#pragma unroll
            for (int it = 0; it < 8; ++it) {
                const int r = it * 8 + r8;
                u.tile[r][c] = s[(size_t)(b0 + r) * HDIM + a0 + c];
            }
            __syncthreads();
#pragma unroll
            for (int it = 0; it < 8; ++it) {
                const int r = it * 8 + r8;
                d[(size_t)(a0 + r) * HDIM + b0 + c] = f2bf(u.tile[c][r]);
            }
            __syncthreads();
        }
    }

    // ================= PHASE 0b: input matmul + LN(0), blocks<128 =========
    if (bx < 128) {
        const int b = bx * 2 + sub;
        if (stid < INDIM) u.inp.xs[sub][stid] = p.x[b * INDIM + stid];
        __syncthreads();
        float acc0 = p.b_in[stid], acc1 = p.b_in[stid + 256], acc2 = p.b_in[stid + 512];
#pragma unroll 8
        for (int i = 0; i < INDIM; ++i) {
            const float xv = u.inp.xs[sub][i];
            acc0 = fmaf(xv, p.w_in[i * HDIM + stid], acc0);
            acc1 = fmaf(xv, p.w_in[i * HDIM + stid + 256], acc1);
            acc2 = fmaf(xv, p.w_in[i * HDIM + stid + 512], acc2);
        }
        p.h[(size_t)b * HDIM + stid] = acc0;
        p.h[(size_t)b * HDIM + stid + 256] = acc1;
        p.h[(size_t)b * HDIM + stid + 512] = acc2;

        float s = acc0 + acc1 + acc2;
        float q = acc0 * acc0 + acc1 * acc1 + acc2 * acc2;
#pragma unroll
        for (int off = 32; off > 0; off >>= 1) { s += __shfl_down(s, off); q += __shfl_down(q, off); }
        if (lane == 0) { u.inp.rbuf[sub][wv] = s; u.inp.rbuf[sub][4 + wv] = q; }
        __syncthreads();
        s = u.inp.rbuf[sub][0] + u.inp.rbuf[sub][1] + u.inp.rbuf[sub][2] + u.inp.rbuf[sub][3];
        q = u.inp.rbuf[sub][4] + u.inp.rbuf[sub][5] + u.inp.rbuf[sub][6] + u.inp.rbuf[sub][7];
        const float mu = s * (1.f / HDIM);
        const float var = q * (1.f / HDIM) - mu * mu;
        const float rsig = rsqrtf(var + 1e-5f);
#pragma unroll
        for (int qq = 0; qq < 3; ++qq) {
            const int o = stid + qq * 256;
            const float av = (qq == 0) ? acc0 : (qq == 1) ? acc1 : acc2;
            const float v = (av - mu) * rsig * p.ln_g[o] + p.ln_b[o];
            p.hnT[(size_t)o * BDIM + b] = v;
            p.hnB[(size_t)b * HDIM + o] = f2bf(v);
        }
    }
    gbar(p.bar, 0);

    // ================= LAYER LOOP ==========================================
    for (int l = 0; l < NLAYERS; ++l) {
        const float* twTl = p.twT + (size_t)l * WSZ;
        const unsigned short* wBl = p.wB + (size_t)(2 * l) * WSZ;

        // ---------------- MM phase ----------------
        if (bx < 192) {
            // tropical fp32 (exact): 384 sub-blocks = 24 spatial x 16 slots
            const int s = bx * 2 + sub;
            const int sp = s % 24;
            const int slot = s / 24;          // 0..15
            const int col0 = (sp % 12) * TC;
            const int row0 = (sp / 12) * TR;
            const int k0 = slot * KLEN;

            const int tx = stid & 15, ty = stid >> 4;
            const int r0 = ty * 8, c0 = tx * 4;
            const int hk = lane >> 5;
            const int hcol = (lane & 31) * 4;
            const int wr = lane >> 4;
            const int wcol = (lane & 15) * 4;

            float t_acc[8][4];
#pragma unroll
            for (int i = 0; i < 8; ++i)
#pragma unroll
                for (int jj = 0; jj < 4; ++jj) t_acc[i][jj] = -1e30f;

            #define STAGE_T(buf, kb)                                                               \
            {                                                                                      \
                gload_lds16(p.hnT + (size_t)((kb) + 4 * wv + hk) * BDIM + row0 + hcol,             \
                            &u.t[sub].hn[buf][4 * wv][0]);                                         \
                gload_lds16(p.hnT + (size_t)((kb) + 4 * wv + 2 + hk) * BDIM + row0 + hcol,         \
                            &u.t[sub].hn[buf][4 * wv + 2][0]);                                     \
                gload_lds16(twTl + (size_t)((kb) + 4 * wv + wr) * HDIM + col0 + wcol,              \
                            &u.t[sub].wt[buf][4 * wv][0]);                                         \
            }

            STAGE_T(0, k0);
            __builtin_amdgcn_s_waitcnt(0);
            __syncthreads();

            for (int c = 0; c < KLEN / CHK; ++c) {
                const int buf = c & 1;
                if (c + 1 < KLEN / CHK) STAGE_T(1 - buf, k0 + (c + 1) * CHK);
#pragma unroll
                for (int k = 0; k < CHK; ++k) {
                    const float4 h0 = *(const float4*)&u.t[sub].hn[buf][k][r0];
                    const float4 h1 = *(const float4*)&u.t[sub].hn[buf][k][r0 + 4];
                    const float4 wt = *(const float4*)&u.t[sub].wt[buf][k][c0];
                    const float hf[8] = {h0.x, h0.y, h0.z, h0.w, h1.x, h1.y, h1.z, h1.w};
                    const float wtf[4] = {wt.x, wt.y, wt.z, wt.w};
#pragma unroll
                    for (int i = 0; i < 8; ++i)
#pragma unroll
                        for (int jj = 0; jj < 4; ++jj)
                            t_acc[i][jj] = fmaxf(t_acc[i][jj], hf[i] + wtf[jj]);
                }
                __builtin_amdgcn_s_waitcnt(0);
                __syncthreads();
            }
            #undef STAGE_T

            const size_t base = (size_t)slot * NBH;
#pragma unroll
            for (int i = 0; i < 8; ++i) {
                const size_t off = base + (size_t)(row0 + r0 + i) * HDIM + col0 + c0;
                *(float4*)(p.p_trop + off) = make_float4(t_acc[i][0], t_acc[i][1], t_acc[i][2], t_acc[i][3]);
            }
        } else {
            // cls+gate bf16 MFMA (HW-verified layouts; R8 absmax 0.0078)
            // 512 wave-units: 16 m-tiles x 2 mats x 16 n-tiles (16x48 each)
            const int idx = (bx - 192) * 8 + wave;   // 0..511
            const int mt = idx >> 5;
            const int rest = idx & 31;
            const int mat = rest >> 4;
            const int nt = rest & 15;
            const int m0 = mt * 16;
            const int n0 = nt * 48;
            const int lm = lane & 15, q = lane >> 4;

            const unsigned short* wmat = wBl + (size_t)mat * WSZ;
            float* pout = mat ? p.p_gate : p.p_cls;

            f32x4 a0v = (f32x4){0.f, 0.f, 0.f, 0.f};
            f32x4 a1v = a0v, a2v = a0v;

            const unsigned short* aptr = p.hnB + (size_t)(m0 + lm) * HDIM + q * 8;
            const unsigned short* b0p = wmat + (size_t)(n0 + lm) * HDIM + q * 8;
            const unsigned short* b1p = b0p + (size_t)16 * HDIM;
            const unsigned short* b2p = b0p + (size_t)32 * HDIM;

#pragma unroll 4
            for (int k0 = 0; k0 < HDIM; k0 += 32) {
                const bf16x8 a  = *(const bf16x8*)(aptr + k0);
                const bf16x8 v0 = *(const bf16x8*)(b0p + k0);
                const bf16x8 v1 = *(const bf16x8*)(b1p + k0);
                const bf16x8 v2 = *(const bf16x8*)(b2p + k0);
                a0v = __builtin_amdgcn_mfma_f32_16x16x32_bf16(a, v0, a0v, 0, 0, 0);
                a1v = __builtin_amdgcn_mfma_f32_16x16x32_bf16(a, v1, a1v, 0, 0, 0);
                a2v = __builtin_amdgcn_mfma_f32_16x16x32_bf16(a, v2, a2v, 0, 0, 0);
            }
#pragma unroll
            for (int r = 0; r < 4; ++r) {
                const size_t rowo = (size_t)(m0 + q * 4 + r) * HDIM + n0 + lm;
                pout[rowo]      = a0v[r];
                pout[rowo + 16] = a1v[r];
                pout[rowo + 32] = a2v[r];
            }
        }
        gbar(p.bar, 1 + 2 * l);

        // ---------------- COMBINE (blocks<128, 2 rows each) ----------------
        if (bx < 128) {
            const int b = bx * 2 + sub;
            const int isl = (l == NLAYERS - 1);
            const float* lg = isl ? p.out_g : p.ln_g + (size_t)(l + 1) * HDIM;
            const float* lb = isl ? p.out_b : p.ln_b + (size_t)(l + 1) * HDIM;

            float hv[3];
            float s = 0.f, q = 0.f;
#pragma unroll
            for (int qq = 0; qq < 3; ++qq) {
                const int o = stid + qq * 256;
                const size_t base = (size_t)b * HDIM + o;
                float tm = -1e30f;
#pragma unroll
                for (int k = 0; k < KSPLIT; ++k)
                    tm = fmaxf(tm, p.p_trop[(size_t)k * NBH + base]);
                const float cs = p.p_cls[base];
                const float gs = p.p_gate[base];

                const float tv = tm + p.trop_b[l * HDIM + o];
                float fmx = -1e30f, fmn = 1e30f;
                const size_t lf = (size_t)l * HDIM * PDIM + (size_t)o * PDIM;
#pragma unroll
                for (int pp = 0; pp < PDIM; ++pp) {
                    fmx = fmaxf(fmx, fmaf(tv, p.amax[lf + pp], p.bmax[lf + pp]));
                    fmn = fminf(fmn, fmaf(tv, p.amin[lf + pp], p.bmin[lf + pp]));
                }
                const float a = sigmoidf_(p.alpha[l * HDIM + o]);
                const float trop_out = a * fmx + (1.f - a) * fmn;
                const float cls_out = geluf_(cs + p.cls_b[l * HDIM + o]);
                const float g = sigmoidf_(gs + p.gate_b[l * HDIM + o]);
                const float val = p.h[base] + g * trop_out + (1.f - g) * cls_out;
                hv[qq] = val;
                p.h[base] = val;
                s += val; q += val * val;
            }

#pragma unroll
            for (int off = 32; off > 0; off >>= 1) { s += __shfl_down(s, off); q += __shfl_down(q, off); }
            if (lane == 0) { u.inp.rbuf[sub][wv] = s; u.inp.rbuf[sub][4 + wv] = q; }
            __syncthreads();
            s = u.inp.rbuf[sub][0] + u.inp.rbuf[sub][1] + u.inp.rbuf[sub][2] + u.inp.rbuf[sub][3];
            q = u.inp.rbuf[sub][4] + u.inp.rbuf[sub][5] + u.inp.rbuf[sub][6] + u.inp.rbuf[sub][7];
            const float mu = s * (1.f / HDIM);
            const float var = q * (1.f / HDIM) - mu * mu;
            const float rsig = rsqrtf(var + 1e-5f);

            if (!isl) {
#pragma unroll
                for (int qq = 0; qq < 3; ++qq) {
                    const int o = stid + qq * 256;
                    const float ln_v = (hv[qq] - mu) * rsig * lg[o] + lb[o];
                    p.hnT[(size_t)o * BDIM + b] = ln_v;
                    p.hnB[(size_t)b * HDIM + o] = f2bf(ln_v);
                }
            } else {
                float part = 0.f;
#pragma unroll
                for (int qq = 0; qq < 3; ++qq) {
                    const int o = stid + qq * 256;
                    part += ((hv[qq] - mu) * rsig * lg[o] + lb[o]) * p.head_w[o];
                }
#pragma unroll
                for (int off = 32; off > 0; off >>= 1) part += __shfl_down(part, off);
                if (lane == 0) u.inp.rbuf[sub][8 + wv] = part;
                __syncthreads();
                if (stid == 0)
                    p.out[b] = u.inp.rbuf[sub][8] + u.inp.rbuf[sub][9]
                             + u.inp.rbuf[sub][10] + u.inp.rbuf[sub][11] + p.head_b[0];
            }
        }
        if (l < NLAYERS - 1) gbar(p.bar, 2 + 2 * l);
    }
}

// ---------------------------------------------------------------------------
extern "C" void kernel_launch(void* const* d_in, const int* in_sizes, int n_in,
                              void* d_out, int out_size, void* d_ws, size_t ws_size,
                              hipStream_t stream)
{
    P pp;
    pp.x      = (const float*)d_in[0];
    pp.w_in   = (const float*)d_in[1];
    pp.b_in   = (const float*)d_in[2];
    pp.ln_g   = (const float*)d_in[3];
    pp.ln_b   = (const float*)d_in[4];
    pp.trop_w = (const float*)d_in[5];
    pp.trop_b = (const float*)d_in[6];
    pp.amax   = (const float*)d_in[7];
    pp.bmax   = (const float*)d_in[8];
    pp.amin   = (const float*)d_in[9];
    pp.bmin   = (const float*)d_in[10];
    pp.alpha  = (const float*)d_in[11];
    pp.gate_w = (const float*)d_in[12];
    pp.gate_b = (const float*)d_in[13];
    pp.cls_w  = (const float*)d_in[14];
    pp.cls_b  = (const float*)d_in[15];
    pp.out_g  = (const float*)d_in[16];
    pp.out_b  = (const float*)d_in[17];
    pp.head_w = (const float*)d_in[18];
    pp.head_b = (const float*)d_in[19];
    pp.out    = (float*)d_out;

    float* ws = (float*)d_ws;
    pp.h      = ws;                                   // NBH
    pp.hnT    = ws + NBH;                             // NBH
    pp.twT    = ws + 2 * NBH;                         // 4*WSZ
    pp.p_trop = pp.twT + (size_t)NLAYERS * WSZ;       // KSPLIT*NBH
    pp.p_cls  = pp.p_trop + (size_t)KSPLIT * NBH;     // NBH
    pp.p_gate = pp.p_cls + NBH;                       // NBH
    pp.hnB    = (unsigned short*)(pp.p_gate + NBH);   // NBH bf16
    pp.wB     = pp.hnB + NBH;                         // 8*WSZ bf16
    pp.bar    = (int*)(pp.wB + 8 * WSZ);              // 16 ints

    hipMemsetAsync(pp.bar, 0, 16 * sizeof(int), stream);
    mega_k<<<NBLKP, NTHR, 0, stream>>>(pp);
}

// Round 14
// 224.237 us; speedup vs baseline: 2.0182x; 2.0182x over previous
//
#include <hip/hip_runtime.h>
#include <math.h>

#define HDIM 768
#define BDIM 256
#define INDIM 64
#define NLAYERS 4
#define PDIM 8
#define KSPLIT 24     // trop k-split: 24 slots x 32k
#define KLEN 32
#define CHK 16
#define TR 128
#define TC 128        // 128x128 trop tile, 8x8 per thread
#define NTROPBLK 288  // 12 spatial x 24 slots
#define NCGBLK 192
#define NBLK (NTROPBLK + NCGBLK)   // 480
#define WSZ ((size_t)HDIM * HDIM)
#define NBH ((size_t)BDIM * HDIM)

typedef short bf16x8 __attribute__((ext_vector_type(8)));
typedef float f32x4 __attribute__((ext_vector_type(4)));

__device__ __forceinline__ float sigmoidf_(float x) { return 1.f / (1.f + expf(-x)); }
__device__ __forceinline__ float geluf_(float x) { return 0.5f * x * (1.f + erff(x * 0.70710678118654752f)); }
__device__ __forceinline__ unsigned short f2bf(float f) {
    unsigned int u = __float_as_uint(f);
    u += 0x7FFFu + ((u >> 16) & 1u);          // RNE
    return (unsigned short)(u >> 16);
}
__device__ __forceinline__ void gload_lds16(const float* g, float* l) {
    __builtin_amdgcn_global_load_lds((const __attribute__((address_space(1))) void*)g,
                                     (__attribute__((address_space(3))) void*)l, 16, 0, 0);
}

// ---------------------------------------------------------------------------
// Merged prep: grid (12,12,12).
//  z<4 : trop_w[l=z] [o][i] fp32 -> twT[l] [i][o] fp32
//  z>=4: zz=z-4, l=zz>>1, mat=zz&1: cls/gate [k][o] fp32 -> wB[l][mat][o][k] bf16
// ---------------------------------------------------------------------------
__global__ __launch_bounds__(256) void prep_k(const float* __restrict__ trop_w,
                                              const float* __restrict__ cls_w,
                                              const float* __restrict__ gate_w,
                                              float* __restrict__ twT,
                                              unsigned short* __restrict__ wB)
{
    __shared__ float tile[64][65];
    const int z = blockIdx.z;
    const int a0 = blockIdx.x * 64;
    const int b0 = blockIdx.y * 64;
    const int c = threadIdx.x & 63;
    const int r4 = threadIdx.x >> 6;

    if (z < NLAYERS) {
        const float* s = trop_w + (size_t)z * WSZ;
        float* d = twT + (size_t)z * WSZ;
#pragma unroll
        for (int it = 0; it < 16; ++it) {
            const int r = it * 4 + r4;
            tile[r][c] = s[(size_t)(a0 + r) * HDIM + b0 + c];
        }
        __syncthreads();
#pragma unroll
        for (int it = 0; it < 16; ++it) {
            const int r = it * 4 + r4;
            d[(size_t)(b0 + r) * HDIM + a0 + c] = tile[c][r];
        }
    } else {
        const int zz = z - NLAYERS;
        const int l = zz >> 1, mat = zz & 1;
        const float* s = (mat ? gate_w : cls_w) + (size_t)l * WSZ;
        unsigned short* d = wB + (size_t)zz * WSZ;
#pragma unroll
        for (int it = 0; it < 16; ++it) {
            const int r = it * 4 + r4;                          // k
            tile[r][c] = s[(size_t)(b0 + r) * HDIM + a0 + c];   // c = o
        }
        __syncthreads();
#pragma unroll
        for (int it = 0; it < 16; ++it) {
            const int r = it * 4 + r4;                          // o
            d[(size_t)(a0 + r) * HDIM + b0 + c] = f2bf(tile[c][r]);
        }
    }
}

// ---------------------------------------------------------------------------
// Kernel 0: h = x @ w_in + b_in, then LN(layer 0) -> hnT (fp32 [k][b]) and
// hnB (bf16 [b][k]).
// ---------------------------------------------------------------------------
__global__ __launch_bounds__(256) void input_ln_k(
    const float* __restrict__ x, const float* __restrict__ w_in,
    const float* __restrict__ b_in,
    const float* __restrict__ lng, const float* __restrict__ lnb,
    float* __restrict__ h, float* __restrict__ hnT, unsigned short* __restrict__ hnB)
{
    const int b = blockIdx.x;
    const int t = threadIdx.x;
    __shared__ float xs[INDIM];
    __shared__ float rbuf[8];
    if (t < INDIM) xs[t] = x[b * INDIM + t];
    __syncthreads();

    float acc0 = b_in[t], acc1 = b_in[t + 256], acc2 = b_in[t + 512];
#pragma unroll 8
    for (int i = 0; i < INDIM; ++i) {
        const float xv = xs[i];
        acc0 = fmaf(xv, w_in[i * HDIM + t], acc0);
        acc1 = fmaf(xv, w_in[i * HDIM + t + 256], acc1);
        acc2 = fmaf(xv, w_in[i * HDIM + t + 512], acc2);
    }
    h[(size_t)b * HDIM + t] = acc0;
    h[(size_t)b * HDIM + t + 256] = acc1;
    h[(size_t)b * HDIM + t + 512] = acc2;

    float s = acc0 + acc1 + acc2;
    float q = acc0 * acc0 + acc1 * acc1 + acc2 * acc2;
#pragma unroll
    for (int off = 32; off > 0; off >>= 1) { s += __shfl_down(s, off); q += __shfl_down(q, off); }
    const int wid = t >> 6, lane = t & 63;
    if (lane == 0) { rbuf[wid] = s; rbuf[4 + wid] = q; }
    __syncthreads();
    s = rbuf[0] + rbuf[1] + rbuf[2] + rbuf[3];
    q = rbuf[4] + rbuf[5] + rbuf[6] + rbuf[7];
    const float mu = s * (1.f / HDIM);
    const float var = q * (1.f / HDIM) - mu * mu;
    const float rsig = rsqrtf(var + 1e-5f);

#pragma unroll
    for (int qq = 0; qq < 3; ++qq) {
        const int o = t + qq * 256;
        const float av = (qq == 0) ? acc0 : (qq == 1) ? acc1 : acc2;
        const float v = (av - mu) * rsig * lng[o] + lnb[o];
        hnT[(size_t)o * BDIM + b] = v;
        hnB[(size_t)b * HDIM + o] = f2bf(v);
    }
}

// ---------------------------------------------------------------------------
// Kernel 1 (per layer, ONE dispatch): block-partitioned fusion (R9/R10 win).
//   blocks [0,288):   TROPICAL fp32, tile 128x128, 8x8/thread (64 accs+temps
//                     ~100 VGPR, fits 128 cap, no spill — R7 precedent).
//                     2x VALU per LDS byte and half the chunk events vs 8x4.
//   blocks [288,480): CLS+GATE bf16 MFMA (HW-verified layouts, R8).
// HW scheduler load-balances the mixed grid (R13 showed static phase
// partitions + barriers lose badly to this).
// ---------------------------------------------------------------------------
__global__ __launch_bounds__(256, 2) void layer_mm_k(
    const float* __restrict__ hnT,        // fp32 [k][b]
    const float* __restrict__ twT,        // fp32 trop_w^T [k][o] (this layer)
    const unsigned short* __restrict__ hnB,  // bf16 [b][k]
    const unsigned short* __restrict__ wB,   // bf16 [mat][o][k] (this layer)
    float* __restrict__ p_trop, float* __restrict__ p_cls, float* __restrict__ p_gate)
{
    __shared__ float hn_s[2][CHK][TR];   // 16 KB (unpadded: global_load_lds)
    __shared__ float wt_s[2][CHK][TC];   // 16 KB

    const int bx = blockIdx.x;
    const int tid = threadIdx.x;
    const int wave = tid >> 6, lane = tid & 63;

    if (bx < NTROPBLK) {
        // ---------------- tropical (fp32, exact) ----------------
        const int sp = bx % 12;
        const int slot = bx / 12;              // 0..23
        const int col0 = (sp % 6) * TC;
        const int row0 = (sp / 6) * TR;
        const int k0 = slot * KLEN;

        const int tx = tid & 15, ty = tid >> 4;
        const int r0 = ty * 8, c0 = tx * 8;

        const int hk = lane >> 5;              // 0/1 within 2-row DMA
        const int hcol = (lane & 31) * 4;      // 0..124

        float t_acc[8][8];
#pragma unroll
        for (int i = 0; i < 8; ++i)
#pragma unroll
            for (int j = 0; j < 8; ++j) t_acc[i][j] = -1e30f;

        // 4 gload_lds16 per wave per chunk: 2 for hn (4 k-rows), 2 for wt
        #define STAGE_T(buf, kb)                                                                   \
        {                                                                                          \
            gload_lds16(hnT + (size_t)((kb) + 4 * wave + hk) * BDIM + row0 + hcol,                 \
                        &hn_s[buf][4 * wave][0]);                                                  \
            gload_lds16(hnT + (size_t)((kb) + 4 * wave + 2 + hk) * BDIM + row0 + hcol,             \
                        &hn_s[buf][4 * wave + 2][0]);                                              \
            gload_lds16(twT + (size_t)((kb) + 4 * wave + hk) * HDIM + col0 + hcol,                 \
                        &wt_s[buf][4 * wave][0]);                                                  \
            gload_lds16(twT + (size_t)((kb) + 4 * wave + 2 + hk) * HDIM + col0 + hcol,             \
                        &wt_s[buf][4 * wave + 2][0]);                                              \
        }

        STAGE_T(0, k0);
        __builtin_amdgcn_s_waitcnt(0);
        __syncthreads();

        for (int c = 0; c < KLEN / CHK; ++c) {
            const int buf = c & 1;
            if (c + 1 < KLEN / CHK) STAGE_T(1 - buf, k0 + (c + 1) * CHK);
#pragma unroll
            for (int k = 0; k < CHK; ++k) {
                const float4 h0 = *(const float4*)&hn_s[buf][k][r0];
                const float4 h1 = *(const float4*)&hn_s[buf][k][r0 + 4];
                const float4 w0 = *(const float4*)&wt_s[buf][k][c0];
                const float4 w1 = *(const float4*)&wt_s[buf][k][c0 + 4];
                const float hf[8] = {h0.x, h0.y, h0.z, h0.w, h1.x, h1.y, h1.z, h1.w};
                const float wf[8] = {w0.x, w0.y, w0.z, w0.w, w1.x, w1.y, w1.z, w1.w};
#pragma unroll
                for (int i = 0; i < 8; ++i)
#pragma unroll
                    for (int j = 0; j < 8; ++j)
                        t_acc[i][j] = fmaxf(t_acc[i][j], hf[i] + wf[j]);
            }
            __builtin_amdgcn_s_waitcnt(0);
            __syncthreads();
        }
        #undef STAGE_T

        const size_t base = (size_t)slot * NBH;
#pragma unroll
        for (int i = 0; i < 8; ++i) {
            const size_t off = base + (size_t)(row0 + r0 + i) * HDIM + col0 + c0;
            *(float4*)(p_trop + off)     = make_float4(t_acc[i][0], t_acc[i][1], t_acc[i][2], t_acc[i][3]);
            *(float4*)(p_trop + off + 4) = make_float4(t_acc[i][4], t_acc[i][5], t_acc[i][6], t_acc[i][7]);
        }
    } else {
        // ---------------- cls+gate (bf16 MFMA, full K, 1 mat/block) --------
        // Layouts (HW-verified R8, absmax 0.0078): A[m=lane&15][k=q*8+j],
        // B[k=q*8+j][n=lane&15], D[m=q*4+r][n=lane&15].
        const int cb = bx - NTROPBLK;          // 0..191
        const int mat = cb & 1;
        const int nt = (cb >> 1) % 24;         // 24 n-tiles of 32
        const int mt = cb / 48;                // 4 m-tiles of 64
        const int m0 = mt * 64 + wave * 16;
        const int n0 = nt * 32;
        const int lm = lane & 15, q = lane >> 4;

        const unsigned short* wmat = wB + (size_t)mat * WSZ;
        float* pout = mat ? p_gate : p_cls;

        f32x4 acc0v = (f32x4){0.f, 0.f, 0.f, 0.f};
        f32x4 acc1v = (f32x4){0.f, 0.f, 0.f, 0.f};

        const unsigned short* aptr = hnB + (size_t)(m0 + lm) * HDIM + q * 8;
        const unsigned short* b0p = wmat + (size_t)(n0 + lm) * HDIM + q * 8;
        const unsigned short* b1p = b0p + (size_t)16 * HDIM;

#pragma unroll 4
        for (int k0 = 0; k0 < HDIM; k0 += 32) {
            const bf16x8 a  = *(const bf16x8*)(aptr + k0);
            const bf16x8 v0 = *(const bf16x8*)(b0p + k0);
            const bf16x8 v1 = *(const bf16x8*)(b1p + k0);
            acc0v = __builtin_amdgcn_mfma_f32_16x16x32_bf16(a, v0, acc0v, 0, 0, 0);
            acc1v = __builtin_amdgcn_mfma_f32_16x16x32_bf16(a, v1, acc1v, 0, 0, 0);
        }
#pragma unroll
        for (int r = 0; r < 4; ++r) {
            pout[(size_t)(m0 + q * 4 + r) * HDIM + n0 + lm]      = acc0v[r];
            pout[(size_t)(m0 + q * 4 + r) * HDIM + n0 + 16 + lm] = acc1v[r];
        }
    }
}

// ---------------------------------------------------------------------------
// Kernel 2 (per layer): reduce trop partials, LF activation, gelu, gate,
// residual, then LN -> hnT/hnB for next layer (or final LN + head -> out).
// ---------------------------------------------------------------------------
__global__ __launch_bounds__(768) void combine_k(
    const float* __restrict__ p_trop, const float* __restrict__ p_cls, const float* __restrict__ p_gate,
    const float* __restrict__ trop_b,
    const float* __restrict__ amax, const float* __restrict__ bmax,
    const float* __restrict__ amin, const float* __restrict__ bmin,
    const float* __restrict__ alpha,
    const float* __restrict__ gate_b, const float* __restrict__ cls_b,
    float* __restrict__ h,
    const float* __restrict__ lng, const float* __restrict__ lnb,
    float* __restrict__ hnT, unsigned short* __restrict__ hnB,
    const float* __restrict__ head_w, const float* __restrict__ head_b,
    float* __restrict__ out, const int is_last)
{
    const int b = blockIdx.x;
    const int o = threadIdx.x;         // 0..767
    __shared__ float rbuf[12], qbuf[12];

    const size_t base = (size_t)b * HDIM + o;
    float tm = -1e30f;
#pragma unroll
    for (int k = 0; k < KSPLIT; ++k)
        tm = fmaxf(tm, p_trop[(size_t)k * NBH + base]);
    const float cs = p_cls[base];
    const float gs = p_gate[base];

    const float tv = tm + trop_b[o];
    float fmx = -1e30f, fmn = 1e30f;
#pragma unroll
    for (int p = 0; p < PDIM; ++p) {
        fmx = fmaxf(fmx, fmaf(tv, amax[o * PDIM + p], bmax[o * PDIM + p]));
        fmn = fminf(fmn, fmaf(tv, amin[o * PDIM + p], bmin[o * PDIM + p]));
    }
    const float a = sigmoidf_(alpha[o]);
    const float trop_out = a * fmx + (1.f - a) * fmn;
    const float cls_out = geluf_(cs + cls_b[o]);
    const float g = sigmoidf_(gs + gate_b[o]);
    const float val = h[base] + g * trop_out + (1.f - g) * cls_out;
    h[base] = val;

    float s = val, q = val * val;
#pragma unroll
    for (int off = 32; off > 0; off >>= 1) { s += __shfl_down(s, off); q += __shfl_down(q, off); }
    const int wid = o >> 6, lane = o & 63;
    if (lane == 0) { rbuf[wid] = s; qbuf[wid] = q; }
    __syncthreads();
    s = 0.f; q = 0.f;
#pragma unroll
    for (int w = 0; w < 12; ++w) { s += rbuf[w]; q += qbuf[w]; }
    const float mu = s * (1.f / HDIM);
    const float var = q * (1.f / HDIM) - mu * mu;
    const float rsig = rsqrtf(var + 1e-5f);
    const float ln_v = (val - mu) * rsig * lng[o] + lnb[o];

    if (!is_last) {
        hnT[(size_t)o * BDIM + b] = ln_v;
        hnB[base] = f2bf(ln_v);
    } else {
        float part = ln_v * head_w[o];
#pragma unroll
        for (int off = 32; off > 0; off >>= 1) part += __shfl_down(part, off);
        __syncthreads();
        if (lane == 0) rbuf[wid] = part;
        __syncthreads();
        if (o == 0) {
            float r = head_b[0];
#pragma unroll
            for (int w = 0; w < 12; ++w) r += rbuf[w];
            out[b] = r;
        }
    }
}

// ---------------------------------------------------------------------------
extern "C" void kernel_launch(void* const* d_in, const int* in_sizes, int n_in,
                              void* d_out, int out_size, void* d_ws, size_t ws_size,
                              hipStream_t stream)
{
    const float* x       = (const float*)d_in[0];
    const float* w_in    = (const float*)d_in[1];
    const float* b_in    = (const float*)d_in[2];
    const float* ln_g    = (const float*)d_in[3];
    const float* ln_b    = (const float*)d_in[4];
    const float* trop_w  = (const float*)d_in[5];
    const float* trop_b  = (const float*)d_in[6];
    const float* lf_amax = (const float*)d_in[7];
    const float* lf_bmax = (const float*)d_in[8];
    const float* lf_amin = (const float*)d_in[9];
    const float* lf_bmin = (const float*)d_in[10];
    const float* lf_alpha= (const float*)d_in[11];
    const float* gate_w  = (const float*)d_in[12];
    const float* gate_b  = (const float*)d_in[13];
    const float* cls_w   = (const float*)d_in[14];
    const float* cls_b   = (const float*)d_in[15];
    const float* out_g   = (const float*)d_in[16];
    const float* out_b   = (const float*)d_in[17];
    const float* head_w  = (const float*)d_in[18];
    const float* head_b  = (const float*)d_in[19];
    float* out = (float*)d_out;

    float* ws = (float*)d_ws;
    float* h      = ws;                               // NBH
    float* hnT    = ws + NBH;                         // NBH fp32 [k][b]
    float* twT    = ws + 2 * NBH;                     // 4*WSZ fp32
    float* p_trop = twT + (size_t)NLAYERS * WSZ;      // KSPLIT*NBH
    float* p_cls  = p_trop + (size_t)KSPLIT * NBH;    // NBH
    float* p_gate = p_cls + NBH;                      // NBH
    unsigned short* hnB = (unsigned short*)(p_gate + NBH);   // NBH bf16
    unsigned short* wB  = hnB + NBH;                         // 8*WSZ bf16

    prep_k<<<dim3(12, 12, 12), 256, 0, stream>>>(trop_w, cls_w, gate_w, twT, wB);
    input_ln_k<<<BDIM, 256, 0, stream>>>(x, w_in, b_in, ln_g, ln_b, h, hnT, hnB);

    for (int l = 0; l < NLAYERS; ++l) {
        layer_mm_k<<<NBLK, 256, 0, stream>>>(
            hnT, twT + (size_t)l * WSZ,
            hnB, wB + (size_t)(2 * l) * WSZ,
            p_trop, p_cls, p_gate);

        const int is_last = (l == NLAYERS - 1);
        combine_k<<<BDIM, 768, 0, stream>>>(
            p_trop, p_cls, p_gate,
            trop_b + (size_t)l * HDIM,
            lf_amax + (size_t)l * HDIM * PDIM, lf_bmax + (size_t)l * HDIM * PDIM,
            lf_amin + (size_t)l * HDIM * PDIM, lf_bmin + (size_t)l * HDIM * PDIM,
            lf_alpha + (size_t)l * HDIM,
            gate_b + (size_t)l * HDIM, cls_b + (size_t)l * HDIM,
            h,
            is_last ? out_g : ln_g + (size_t)(l + 1) * HDIM,
            is_last ? out_b : ln_b + (size_t)(l + 1) * HDIM,
            hnT, hnB, head_w, head_b, out, is_last);
    }
}